// Round 4
// baseline (134.492 us; speedup 1.0000x reference)
//
#include <hip/hip_runtime.h>
#include <cstddef>

// Problem constants: (B,W,D,H,C) = (2,16,16,16,32), N = 4096 per batch.
//
// Reference-semantics note (learned in R2 post-mortem): the reference's
// reshape(B,-1,N) is a row-major FLAT reshape: K[r][n] = Kflat[r*4096+n]
// where Kflat[sp*8+ch] is natural projection order. Qf/Kf/Jf are therefore
// stored FLAT (sp*8+ch) and consumed as [r*4096+n] — that IS the reference.
// M = K@Jt must be the exact flat pairing: M[r][s] = sum_n Kflat[r*4096+n]*
// Jflat[s*4096+n] (cross-spatial-block) — computed in kM, not in kA.
// The sigmoid is ~saturated (z ~ 400) for typical rows, but tail rows
// (sigma = 1-delta) accumulate sum_j delta*V ~ O(1): z must be
// reference-exact per-row or absmax blows past threshold.

typedef short bf16x8 __attribute__((ext_vector_type(8)));
typedef float f32x4 __attribute__((ext_vector_type(4)));

__device__ __forceinline__ unsigned short f2bf(float f) {
    union { float f; unsigned u; } v; v.f = f;
    unsigned r = v.u + 0x7fffu + ((v.u >> 16) & 1u);   // RNE
    return (unsigned short)(r >> 16);
}

// ---------------------------------------------------------------------------
// Kernel A: fused Q/K/J/V projections + out=x passthrough.
// Grid 1024 x 256 threads = 8 spatial points x 32 groups.
// Outputs:
//   Qf,Kf,Jf fp32 flat [b][sp*8+ch]  (reference reshape semantics)
//   Vt bf16 [b][c*4096+sp], gamma pre-folded
//   out = x (replaces the D2D memcpy dispatch)
// ---------------------------------------------------------------------------
__global__ __launch_bounds__(256) void kA(
    const float* __restrict__ x,
    const float* __restrict__ qw, const float* __restrict__ qb,
    const float* __restrict__ qs, const float* __restrict__ qo,
    const float* __restrict__ kw, const float* __restrict__ kb,
    const float* __restrict__ ks, const float* __restrict__ ko,
    const float* __restrict__ jw, const float* __restrict__ jb,
    const float* __restrict__ js, const float* __restrict__ jo,
    const float* __restrict__ vw, const float* __restrict__ vb,
    const float* __restrict__ vs, const float* __restrict__ vo,
    const float* __restrict__ gamma,
    float* __restrict__ Qf, float* __restrict__ Kf, float* __restrict__ Jf,
    unsigned short* __restrict__ Vt, float* __restrict__ out)
{
    __shared__ float vw_s[1024];        // [ci][co]
    __shared__ float cw_s[3 * 776];     // conv weights [conv][tap*256+ci*8+co]
    const int t = threadIdx.x;
    for (int i = t; i < 1024; i += 256) vw_s[i] = vw[i];
    for (int i = t; i < 768; i += 256) {
        cw_s[i]        = qw[i];
        cw_s[776 + i]  = kw[i];
        cw_s[1552 + i] = jw[i];
    }
    __syncthreads();

    const int spi = t >> 5;                     // 8 spatial points per block
    const int g   = t & 31;                     // 32 groups per point
    const int gsp = blockIdx.x * 8 + spi;       // b*4096+sp (b uniform per block)
    const int b   = gsp >> 12;
    const int sp  = gsp & 4095;
    const int w = sp >> 8, d = (sp >> 4) & 15, h = sp & 15;
    const float gm = gamma[0];
    const float4* xr = (const float4*)(x + (size_t)gsp * 32);

    // own x row in registers (shared by V-dot, center tap, and out passthrough)
    float4 xv[8];
    #pragma unroll
    for (int c8 = 0; c8 < 8; ++c8) xv[c8] = xr[c8];

    // out = x (each thread writes its one element; coalesced)
    {
        const float4 mine = xv[g >> 2];
        const int q = g & 3;
        const float xe = (q == 0) ? mine.x : (q == 1) ? mine.y : (q == 2) ? mine.z : mine.w;
        out[(size_t)gsp * 32 + g] = xe;
    }

    // ---- V (pointwise 32->32): one output channel (co=g) per thread ----
    {
        float a0 = 0.f, a1 = 0.f, a2 = 0.f, a3 = 0.f;
        #pragma unroll
        for (int c8 = 0; c8 < 8; ++c8) {
            const float4 v = xv[c8];
            a0 += v.x * vw_s[(c8 * 4 + 0) * 32 + g];
            a1 += v.y * vw_s[(c8 * 4 + 1) * 32 + g];
            a2 += v.z * vw_s[(c8 * 4 + 2) * 32 + g];
            a3 += v.w * vw_s[(c8 * 4 + 3) * 32 + g];
        }
        const float vv = fmaxf(((a0 + a1) + (a2 + a3) + vb[g]) * vs[g] + vo[g], 0.f) * gm;
        Vt[(size_t)b * 131072 + (size_t)g * 4096 + sp] = f2bf(vv);
    }

    // ---- Q/K/J (3-tap 1-D convs along d/w/h): one output per thread, g<24 ----
    if (g < 24) {
        const int conv = g >> 3;               // 0=Q(d), 1=K(w), 2=J(h)
        const int co   = g & 7;
        const int coord  = (conv == 0) ? d : (conv == 1) ? w : h;
        const int stride = (conv == 0) ? 16 : (conv == 1) ? 256 : 1;
        const float* cw = cw_s + conv * 776 + co;
        float b0 = 0.f, b1 = 0.f, b2 = 0.f, b3 = 0.f;
        #pragma unroll
        for (int tap = 0; tap < 3; ++tap) {
            const int cc = coord + tap - 1;
            if (cc < 0 || cc > 15) continue;           // SAME zero-pad
            const float4* xt = (const float4*)(x + (size_t)(gsp + (tap - 1) * stride) * 32);
            const float* wt = cw + tap * 256;
            #pragma unroll
            for (int c8 = 0; c8 < 8; ++c8) {
                const float4 v = (tap == 1) ? xv[c8] : xt[c8];  // center tap from regs
                b0 += v.x * wt[(c8 * 4 + 0) * 8];
                b1 += v.y * wt[(c8 * 4 + 1) * 8];
                b2 += v.z * wt[(c8 * 4 + 2) * 8];
                b3 += v.w * wt[(c8 * 4 + 3) * 8];
            }
        }
        const float* bbp = (conv == 0) ? qb : (conv == 1) ? kb : jb;
        const float* scp = (conv == 0) ? qs : (conv == 1) ? ks : js;
        const float* oop = (conv == 0) ? qo : (conv == 1) ? ko : jo;
        const float rv = fmaxf(((b0 + b1) + (b2 + b3) + bbp[co]) * scp[co] + oop[co], 0.f);
        float* dst = (conv == 0) ? Qf : (conv == 1) ? Kf : Jf;
        dst[(size_t)b * 32768 + (size_t)sp * 8 + co] = rv;   // FLAT (reference)
    }
}

// ---------------------------------------------------------------------------
// Kernel M: exact reference M = K@Jt on the flat matrices.
// M[b][r][s] = sum_n Kflat[r*4096+n] * Jflat[s*4096+n].
// Grid 16 blocks (b*8+octant) x 256 threads; Mm pre-zeroed (128 floats).
// ---------------------------------------------------------------------------
__global__ __launch_bounds__(256) void kM(
    const float* __restrict__ Kf, const float* __restrict__ Jf,
    float* __restrict__ Mm)
{
    const int b = blockIdx.x >> 3, o = blockIdx.x & 7;
    const int t = threadIdx.x;
    const int rs = t & 63, r = rs >> 3, s = rs & 7, sub = t >> 6;
    const float4* Kb = (const float4*)(Kf + (size_t)b * 32768 + (size_t)r * 4096 + o * 512 + sub * 128);
    const float4* Jb = (const float4*)(Jf + (size_t)b * 32768 + (size_t)s * 4096 + o * 512 + sub * 128);
    float acc = 0.f;
    #pragma unroll
    for (int i = 0; i < 32; ++i) {
        const float4 kv = Kb[i];
        const float4 jv = Jb[i];
        acc += kv.x * jv.x + kv.y * jv.y + kv.z * jv.z + kv.w * jv.w;
    }
    __shared__ float sm[256];
    sm[t] = acc;
    __syncthreads();
    if (t < 64)
        atomicAdd(&Mm[b * 64 + t], sm[t] + sm[t + 64] + sm[t + 128] + sm[t + 192]);
}

// ---------------------------------------------------------------------------
// Kernel D: out[b][i][c] += sum_{j in split} sigmoid(P_i.Kcol_j) * (gamma*V)[j][c]
// (out pre-initialized to x by kA; gamma folded into Vt by kA.)
// Block: 256 threads = 4 waves, TI=64 rows, j-split of 512 (8 chunks of 64).
// Grid: 2b x 64 rowtiles x 8 jsplits = 1024 blocks (LDS ~35 KB).
// Verified layouts (m89/m120): A[m=lane&15][k=quad*8+j]; B[k=quad*8+j][n=lane&15];
// C/D: col=lane&15, row=quad*4+reg.
// ---------------------------------------------------------------------------
__global__ __launch_bounds__(256) void kD(
    const float* __restrict__ Qf, const float* __restrict__ Mm,
    const float* __restrict__ Kf, const unsigned short* __restrict__ Vt,
    float* __restrict__ out)
{
    const int blk = blockIdx.x;
    const int jsp = blk & 7;
    const int rt  = (blk >> 3) & 63;
    const int b   = blk >> 9;
    const int i0  = rt * 64;
    const int j0  = jsp * 512;
    const int t   = threadIdx.x;
    // phase-1 mapping: 16 rowgroups (4 rows) x 16 jgroups (4 j)
    const int jg = t & 15, rg = t >> 4;
    // phase-2 mapping: wave w covers rows w*16..w*16+15
    const int w = t >> 6, lane = t & 63;
    const int m = lane & 15, quad = lane >> 4;

    __shared__ float m_s[64];
    __shared__ float kt_s[8][516];              // whole K chunk [r][j0-relative j]
    __shared__ unsigned short s_lds[2][64][72]; // sigmoid tile bf16, double-buffered

    const float* Kb = Kf + (size_t)b * 32768;
    const unsigned short* Vb = Vt + (size_t)b * 131072;

    if (t < 64) m_s[t] = Mm[b * 64 + t];
    #pragma unroll
    for (int v = 0; v < 4; ++v) {               // stage 8x512 fp32 K rows once
        const int idx = t + v * 256;            // 0..1023 float4s
        const int r = idx >> 7, j4 = (idx & 127) << 2;
        *(float4*)&kt_s[r][j4] = *(const float4*)(Kb + (size_t)r * 4096 + j0 + j4);
    }
    __syncthreads();

    // P2[4 rows][8] = -log2(e) * (Qt-rows . M); Qt[i][r] = Qflat[r*4096+i]
    float P2[4][8];
    {
        float a[4][8];
        #pragma unroll
        for (int r = 0; r < 8; ++r) {
            const float4 qv = *(const float4*)(Qf + (size_t)b * 32768 + (size_t)r * 4096 + i0 + rg * 4);
            a[0][r] = qv.x; a[1][r] = qv.y; a[2][r] = qv.z; a[3][r] = qv.w;
        }
        #pragma unroll
        for (int s = 0; s < 8; ++s) {
            #pragma unroll
            for (int ri = 0; ri < 4; ++ri) {
                float acc = 0.f;
                #pragma unroll
                for (int r = 0; r < 8; ++r) acc += a[ri][r] * m_s[r * 8 + s];
                P2[ri][s] = acc * -1.44269504f;
            }
        }
    }

    f32x4 acc0 = {0.f, 0.f, 0.f, 0.f};
    f32x4 acc1 = {0.f, 0.f, 0.f, 0.f};

    #pragma unroll 1
    for (int jc = 0; jc < 8; ++jc) {
        const int jb = j0 + jc * 64;
        // prefetch B frags; the barrier's vmcnt(0) drain is exactly their use site
        const bf16x8 bv00 = *(const bf16x8*)(Vb + (size_t)m * 4096 + jb + quad * 8);
        const bf16x8 bv10 = *(const bf16x8*)(Vb + (size_t)m * 4096 + jb + 32 + quad * 8);
        const bf16x8 bv01 = *(const bf16x8*)(Vb + (size_t)(16 + m) * 4096 + jb + quad * 8);
        const bf16x8 bv11 = *(const bf16x8*)(Vb + (size_t)(16 + m) * 4096 + jb + 32 + quad * 8);

        unsigned short (*sl)[72] = s_lds[jc & 1];

        // phase 1: 16 sigmoids per thread (4 rows x 4 j), bf16 tile to sl
        unsigned hpk[4][2];
        {
            f32x4 pa[4];
            #pragma unroll
            for (int ri = 0; ri < 4; ++ri) pa[ri] = (f32x4){0.f, 0.f, 0.f, 0.f};
            #pragma unroll
            for (int r = 0; r < 8; ++r) {
                const f32x4 kv = *(const f32x4*)&kt_s[r][(jc << 6) + (jg << 2)];
                #pragma unroll
                for (int ri = 0; ri < 4; ++ri) {
                    const float p = P2[ri][r];
                    pa[ri][0] += p * kv[0];
                    pa[ri][1] += p * kv[1];
                    pa[ri][2] += p * kv[2];
                    pa[ri][3] += p * kv[3];
                }
            }
            #pragma unroll
            for (int ri = 0; ri < 4; ++ri) {
                float e0, e1, e2, e3;
                asm("v_exp_f32 %0, %1" : "=v"(e0) : "v"(pa[ri][0]));
                asm("v_exp_f32 %0, %1" : "=v"(e1) : "v"(pa[ri][1]));
                asm("v_exp_f32 %0, %1" : "=v"(e2) : "v"(pa[ri][2]));
                asm("v_exp_f32 %0, %1" : "=v"(e3) : "v"(pa[ri][3]));
                const float s0 = __builtin_amdgcn_rcpf(1.0f + e0);
                const float s1 = __builtin_amdgcn_rcpf(1.0f + e1);
                const float s2 = __builtin_amdgcn_rcpf(1.0f + e2);
                const float s3 = __builtin_amdgcn_rcpf(1.0f + e3);
                unsigned pk0, pk1;
                asm("v_cvt_pk_bf16_f32 %0, %1, %2" : "=v"(pk0) : "v"(s0), "v"(s1));
                asm("v_cvt_pk_bf16_f32 %0, %1, %2" : "=v"(pk1) : "v"(s2), "v"(s3));
                hpk[ri][0] = pk0;
                hpk[ri][1] = pk1;
            }
        }
        #pragma unroll
        for (int ri = 0; ri < 4; ++ri)
            *(uint2*)&sl[rg * 4 + ri][jg * 4] = make_uint2(hpk[ri][0], hpk[ri][1]);

        __syncthreads();

        // phase 2: 4 MFMAs per wave (2 k-tiles x 2 n-tiles), B from regs
        __builtin_amdgcn_s_setprio(1);
        const bf16x8 af0 = *(const bf16x8*)&sl[w * 16 + m][quad * 8];
        const bf16x8 af1 = *(const bf16x8*)&sl[w * 16 + m][32 + quad * 8];
        acc0 = __builtin_amdgcn_mfma_f32_16x16x32_bf16(af0, bv00, acc0, 0, 0, 0);
        acc1 = __builtin_amdgcn_mfma_f32_16x16x32_bf16(af0, bv01, acc1, 0, 0, 0);
        acc0 = __builtin_amdgcn_mfma_f32_16x16x32_bf16(af1, bv10, acc0, 0, 0, 0);
        acc1 = __builtin_amdgcn_mfma_f32_16x16x32_bf16(af1, bv11, acc1, 0, 0, 0);
        __builtin_amdgcn_s_setprio(0);
    }

    // epilogue: atomic accumulate partials onto out (pre-set to x; gamma in Vt)
    #pragma unroll
    for (int reg = 0; reg < 4; ++reg) {
        const int row = i0 + w * 16 + quad * 4 + reg;
        float* op = out + ((size_t)b * 4096 + row) * 32 + m;
        atomicAdd(op,      acc0[reg]);
        atomicAdd(op + 16, acc1[reg]);
    }
}

// ---------------------------------------------------------------------------
extern "C" void kernel_launch(void* const* d_in, const int* in_sizes, int n_in,
                              void* d_out, int out_size, void* d_ws, size_t ws_size,
                              hipStream_t stream)
{
    const float* x     = (const float*)d_in[0];
    const float* gamma = (const float*)d_in[1];
    const float* qw = (const float*)d_in[2];
    const float* qb = (const float*)d_in[3];
    const float* qs = (const float*)d_in[4];
    const float* qo = (const float*)d_in[5];
    const float* kw = (const float*)d_in[6];
    const float* kb = (const float*)d_in[7];
    const float* ks = (const float*)d_in[8];
    const float* ko = (const float*)d_in[9];
    const float* jw = (const float*)d_in[10];
    const float* jb = (const float*)d_in[11];
    const float* js = (const float*)d_in[12];
    const float* jo = (const float*)d_in[13];
    const float* vw = (const float*)d_in[14];
    const float* vb = (const float*)d_in[15];
    const float* vs = (const float*)d_in[16];
    const float* vo = (const float*)d_in[17];

    float* ws = (float*)d_ws;
    float* Qf = ws;                                   // 65536 floats
    float* Kf = ws + 65536;                           // 65536
    float* Jf = ws + 131072;                          // 65536
    float* Mm = ws + 196608;                          // 128
    unsigned short* Vt = (unsigned short*)(ws + 196736); // 262144 bf16 (16B-aligned)

    hipMemsetAsync(Mm, 0, 128 * sizeof(float), stream);
    kA<<<1024, 256, 0, stream>>>(x, qw, qb, qs, qo, kw, kb, ks, ko,
                                 jw, jb, js, jo, vw, vb, vs, vo, gamma,
                                 Qf, Kf, Jf, Vt, (float*)d_out);
    kM<<<16, 256, 0, stream>>>(Kf, Jf, Mm);
    kD<<<1024, 256, 0, stream>>>(Qf, Mm, Kf, Vt, (float*)d_out);
}

// Round 6
// 133.574 us; speedup vs baseline: 1.0069x; 1.0069x over previous
//
#include <hip/hip_runtime.h>
#include <cstddef>

// Problem constants: (B,W,D,H,C) = (2,16,16,16,32), N = 4096 per batch.
//
// Reference-semantics note (R2 post-mortem): reshape(B,-1,N) is a row-major
// FLAT reshape: K[r][n] = Kflat[r*4096+n], Kflat[sp*8+ch] natural projection
// order. Qf/Kf/Jf stored FLAT, consumed as [r*4096+n] — that IS the reference.
// M[r][s] = sum_n Kflat[r*4096+n]*Jflat[s*4096+n] (cross-spatial pairing),
// computed exactly in kM. Sigmoid is ~saturated for typical rows but tail rows
// accumulate sum_j delta*V ~ O(1): z must be reference-exact per-row.
// R4 confirmed: exact M gives absmax 0.03125 (bf16-V random-walk floor).
//
// R5 post-mortem: fusing the three kernels into one cooperative kernel with
// cg::this_grid().sync() produced a ~2% partial-staleness error (absmax 8.6)
// — cross-XCD visibility of plain stores across grid.sync is not reliable
// here (Guideline 16). Kernel-dispatch boundaries are the trustworthy fence.
// Kept from R5: atomic-free octant-slice kM (drops the memset dispatch).

typedef short bf16x8 __attribute__((ext_vector_type(8)));
typedef float f32x4 __attribute__((ext_vector_type(4)));

__device__ __forceinline__ unsigned short f2bf(float f) {
    union { float f; unsigned u; } v; v.f = f;
    unsigned r = v.u + 0x7fffu + ((v.u >> 16) & 1u);   // RNE
    return (unsigned short)(r >> 16);
}

// ---------------------------------------------------------------------------
// Kernel A: fused Q/K/J/V projections + out=x passthrough.
// Grid 1024 x 256 threads = 8 spatial points x 32 groups.
// Outputs:
//   Qf,Kf,Jf fp32 flat [b][sp*8+ch]  (reference reshape semantics)
//   Vt bf16 [b][c*4096+sp], gamma pre-folded
//   out = x (replaces the D2D memcpy dispatch)
// ---------------------------------------------------------------------------
__global__ __launch_bounds__(256) void kA(
    const float* __restrict__ x,
    const float* __restrict__ qw, const float* __restrict__ qb,
    const float* __restrict__ qs, const float* __restrict__ qo,
    const float* __restrict__ kw, const float* __restrict__ kb,
    const float* __restrict__ ks, const float* __restrict__ ko,
    const float* __restrict__ jw, const float* __restrict__ jb,
    const float* __restrict__ js, const float* __restrict__ jo,
    const float* __restrict__ vw, const float* __restrict__ vb,
    const float* __restrict__ vs, const float* __restrict__ vo,
    const float* __restrict__ gamma,
    float* __restrict__ Qf, float* __restrict__ Kf, float* __restrict__ Jf,
    unsigned short* __restrict__ Vt, float* __restrict__ out)
{
    __shared__ float vw_s[1024];        // [ci][co]
    __shared__ float cw_s[3 * 776];     // conv weights [conv][tap*256+ci*8+co]
    const int t = threadIdx.x;
    for (int i = t; i < 1024; i += 256) vw_s[i] = vw[i];
    for (int i = t; i < 768; i += 256) {
        cw_s[i]        = qw[i];
        cw_s[776 + i]  = kw[i];
        cw_s[1552 + i] = jw[i];
    }
    __syncthreads();

    const int spi = t >> 5;                     // 8 spatial points per block
    const int g   = t & 31;                     // 32 groups per point
    const int gsp = blockIdx.x * 8 + spi;       // b*4096+sp (b uniform per block)
    const int b   = gsp >> 12;
    const int sp  = gsp & 4095;
    const int w = sp >> 8, d = (sp >> 4) & 15, h = sp & 15;
    const float gm = gamma[0];
    const float4* xr = (const float4*)(x + (size_t)gsp * 32);

    // own x row in registers (shared by V-dot, center tap, and out passthrough)
    float4 xv[8];
    #pragma unroll
    for (int c8 = 0; c8 < 8; ++c8) xv[c8] = xr[c8];

    // out = x (each thread writes its one element; coalesced)
    {
        const float4 mine = xv[g >> 2];
        const int q = g & 3;
        const float xe = (q == 0) ? mine.x : (q == 1) ? mine.y : (q == 2) ? mine.z : mine.w;
        out[(size_t)gsp * 32 + g] = xe;
    }

    // ---- V (pointwise 32->32): one output channel (co=g) per thread ----
    {
        float a0 = 0.f, a1 = 0.f, a2 = 0.f, a3 = 0.f;
        #pragma unroll
        for (int c8 = 0; c8 < 8; ++c8) {
            const float4 v = xv[c8];
            a0 += v.x * vw_s[(c8 * 4 + 0) * 32 + g];
            a1 += v.y * vw_s[(c8 * 4 + 1) * 32 + g];
            a2 += v.z * vw_s[(c8 * 4 + 2) * 32 + g];
            a3 += v.w * vw_s[(c8 * 4 + 3) * 32 + g];
        }
        const float vv = fmaxf(((a0 + a1) + (a2 + a3) + vb[g]) * vs[g] + vo[g], 0.f) * gm;
        Vt[(size_t)b * 131072 + (size_t)g * 4096 + sp] = f2bf(vv);
    }

    // ---- Q/K/J (3-tap 1-D convs along d/w/h): one output per thread, g<24 ----
    if (g < 24) {
        const int conv = g >> 3;               // 0=Q(d), 1=K(w), 2=J(h)
        const int co   = g & 7;
        const int coord  = (conv == 0) ? d : (conv == 1) ? w : h;
        const int stride = (conv == 0) ? 16 : (conv == 1) ? 256 : 1;
        const float* cw = cw_s + conv * 776 + co;
        float b0 = 0.f, b1 = 0.f, b2 = 0.f, b3 = 0.f;
        #pragma unroll
        for (int tap = 0; tap < 3; ++tap) {
            const int cc = coord + tap - 1;
            if (cc < 0 || cc > 15) continue;           // SAME zero-pad
            const float4* xt = (const float4*)(x + (size_t)(gsp + (tap - 1) * stride) * 32);
            const float* wt = cw + tap * 256;
            #pragma unroll
            for (int c8 = 0; c8 < 8; ++c8) {
                const float4 v = (tap == 1) ? xv[c8] : xt[c8];  // center tap from regs
                b0 += v.x * wt[(c8 * 4 + 0) * 8];
                b1 += v.y * wt[(c8 * 4 + 1) * 8];
                b2 += v.z * wt[(c8 * 4 + 2) * 8];
                b3 += v.w * wt[(c8 * 4 + 3) * 8];
            }
        }
        const float* bbp = (conv == 0) ? qb : (conv == 1) ? kb : jb;
        const float* scp = (conv == 0) ? qs : (conv == 1) ? ks : js;
        const float* oop = (conv == 0) ? qo : (conv == 1) ? ko : jo;
        const float rv = fmaxf(((b0 + b1) + (b2 + b3) + bbp[co]) * scp[co] + oop[co], 0.f);
        float* dst = (conv == 0) ? Qf : (conv == 1) ? Kf : Jf;
        dst[(size_t)b * 32768 + (size_t)sp * 8 + co] = rv;   // FLAT (reference)
    }
}

// ---------------------------------------------------------------------------
// Kernel M: exact reference M = K@Jt on the flat matrices, octant slices.
// Mp[o][b*64 + r*8 + s] = sum_{n in octant o} Kflat[r*4096+n]*Jflat[s*4096+n].
// Plain disjoint stores — no atomics, no pre-zero needed.
// Grid 16 blocks (b*8+octant) x 256 threads.
// ---------------------------------------------------------------------------
__global__ __launch_bounds__(256) void kM(
    const float* __restrict__ Kf, const float* __restrict__ Jf,
    float* __restrict__ Mp)
{
    const int b = blockIdx.x >> 3, o = blockIdx.x & 7;
    const int t = threadIdx.x;
    const int rs = t & 63, r = rs >> 3, s = rs & 7, sub = t >> 6;
    const float4* Kb = (const float4*)(Kf + (size_t)b * 32768 + (size_t)r * 4096 + o * 512 + sub * 128);
    const float4* Jb = (const float4*)(Jf + (size_t)b * 32768 + (size_t)s * 4096 + o * 512 + sub * 128);
    float acc = 0.f;
    #pragma unroll
    for (int i = 0; i < 32; ++i) {
        const float4 kv = Kb[i];
        const float4 jv = Jb[i];
        acc += kv.x * jv.x + kv.y * jv.y + kv.z * jv.z + kv.w * jv.w;
    }
    __shared__ float sm[256];
    sm[t] = acc;
    __syncthreads();
    if (t < 64)
        Mp[o * 128 + b * 64 + t] = sm[t] + sm[t + 64] + sm[t + 128] + sm[t + 192];
}

// ---------------------------------------------------------------------------
// Kernel D: out[b][i][c] += sum_{j in split} sigmoid(P_i.Kcol_j) * (gamma*V)[j][c]
// (out pre-initialized to x by kA; gamma folded into Vt by kA.)
// Block: 256 threads = 4 waves, TI=64 rows, j-split of 512 (8 chunks of 64).
// Grid: 2b x 64 rowtiles x 8 jsplits = 1024 blocks (LDS ~35 KB).
// Verified layouts (m89/m120): A[m=lane&15][k=quad*8+j]; B[k=quad*8+j][n=lane&15];
// C/D: col=lane&15, row=quad*4+reg.
// ---------------------------------------------------------------------------
__global__ __launch_bounds__(256) void kD(
    const float* __restrict__ Qf, const float* __restrict__ Mp,
    const float* __restrict__ Kf, const unsigned short* __restrict__ Vt,
    float* __restrict__ out)
{
    const int blk = blockIdx.x;
    const int jsp = blk & 7;
    const int rt  = (blk >> 3) & 63;
    const int b   = blk >> 9;
    const int i0  = rt * 64;
    const int j0  = jsp * 512;
    const int t   = threadIdx.x;
    // phase-1 mapping: 16 rowgroups (4 rows) x 16 jgroups (4 j)
    const int jg = t & 15, rg = t >> 4;
    // phase-2 mapping: wave w covers rows w*16..w*16+15
    const int w = t >> 6, lane = t & 63;
    const int m = lane & 15, quad = lane >> 4;

    __shared__ float m_s[64];
    __shared__ float kt_s[8][516];              // whole K chunk [r][j0-relative j]
    __shared__ unsigned short s_lds[2][64][72]; // sigmoid tile bf16, double-buffered

    const float* Kb = Kf + (size_t)b * 32768;
    const unsigned short* Vb = Vt + (size_t)b * 131072;

    if (t < 64) {
        const int e = b * 64 + t;
        float ms = 0.f;
        #pragma unroll
        for (int o = 0; o < 8; ++o) ms += Mp[o * 128 + e];
        m_s[t] = ms;
    }
    #pragma unroll
    for (int v = 0; v < 4; ++v) {               // stage 8x512 fp32 K rows once
        const int idx = t + v * 256;            // 0..1023 float4s
        const int r = idx >> 7, j4 = (idx & 127) << 2;
        *(float4*)&kt_s[r][j4] = *(const float4*)(Kb + (size_t)r * 4096 + j0 + j4);
    }
    __syncthreads();

    // P2[4 rows][8] = -log2(e) * (Qt-rows . M); Qt[i][r] = Qflat[r*4096+i]
    float P2[4][8];
    {
        float a[4][8];
        #pragma unroll
        for (int r = 0; r < 8; ++r) {
            const float4 qv = *(const float4*)(Qf + (size_t)b * 32768 + (size_t)r * 4096 + i0 + rg * 4);
            a[0][r] = qv.x; a[1][r] = qv.y; a[2][r] = qv.z; a[3][r] = qv.w;
        }
        #pragma unroll
        for (int s = 0; s < 8; ++s) {
            #pragma unroll
            for (int ri = 0; ri < 4; ++ri) {
                float acc = 0.f;
                #pragma unroll
                for (int r = 0; r < 8; ++r) acc += a[ri][r] * m_s[r * 8 + s];
                P2[ri][s] = acc * -1.44269504f;
            }
        }
    }

    f32x4 acc0 = {0.f, 0.f, 0.f, 0.f};
    f32x4 acc1 = {0.f, 0.f, 0.f, 0.f};

    #pragma unroll 1
    for (int jc = 0; jc < 8; ++jc) {
        const int jb = j0 + jc * 64;
        // prefetch B frags; the barrier's vmcnt(0) drain is exactly their use site
        const bf16x8 bv00 = *(const bf16x8*)(Vb + (size_t)m * 4096 + jb + quad * 8);
        const bf16x8 bv10 = *(const bf16x8*)(Vb + (size_t)m * 4096 + jb + 32 + quad * 8);
        const bf16x8 bv01 = *(const bf16x8*)(Vb + (size_t)(16 + m) * 4096 + jb + quad * 8);
        const bf16x8 bv11 = *(const bf16x8*)(Vb + (size_t)(16 + m) * 4096 + jb + 32 + quad * 8);

        unsigned short (*sl)[72] = s_lds[jc & 1];

        // phase 1: 16 sigmoids per thread (4 rows x 4 j), bf16 tile to sl
        unsigned hpk[4][2];
        {
            f32x4 pa[4];
            #pragma unroll
            for (int ri = 0; ri < 4; ++ri) pa[ri] = (f32x4){0.f, 0.f, 0.f, 0.f};
            #pragma unroll
            for (int r = 0; r < 8; ++r) {
                const f32x4 kv = *(const f32x4*)&kt_s[r][(jc << 6) + (jg << 2)];
                #pragma unroll
                for (int ri = 0; ri < 4; ++ri) {
                    const float p = P2[ri][r];
                    pa[ri][0] += p * kv[0];
                    pa[ri][1] += p * kv[1];
                    pa[ri][2] += p * kv[2];
                    pa[ri][3] += p * kv[3];
                }
            }
            #pragma unroll
            for (int ri = 0; ri < 4; ++ri) {
                float e0, e1, e2, e3;
                asm("v_exp_f32 %0, %1" : "=v"(e0) : "v"(pa[ri][0]));
                asm("v_exp_f32 %0, %1" : "=v"(e1) : "v"(pa[ri][1]));
                asm("v_exp_f32 %0, %1" : "=v"(e2) : "v"(pa[ri][2]));
                asm("v_exp_f32 %0, %1" : "=v"(e3) : "v"(pa[ri][3]));
                const float s0 = __builtin_amdgcn_rcpf(1.0f + e0);
                const float s1 = __builtin_amdgcn_rcpf(1.0f + e1);
                const float s2 = __builtin_amdgcn_rcpf(1.0f + e2);
                const float s3 = __builtin_amdgcn_rcpf(1.0f + e3);
                unsigned pk0, pk1;
                asm("v_cvt_pk_bf16_f32 %0, %1, %2" : "=v"(pk0) : "v"(s0), "v"(s1));
                asm("v_cvt_pk_bf16_f32 %0, %1, %2" : "=v"(pk1) : "v"(s2), "v"(s3));
                hpk[ri][0] = pk0;
                hpk[ri][1] = pk1;
            }
        }
        #pragma unroll
        for (int ri = 0; ri < 4; ++ri)
            *(uint2*)&sl[rg * 4 + ri][jg * 4] = make_uint2(hpk[ri][0], hpk[ri][1]);

        __syncthreads();

        // phase 2: 4 MFMAs per wave (2 k-tiles x 2 n-tiles), B from regs
        __builtin_amdgcn_s_setprio(1);
        const bf16x8 af0 = *(const bf16x8*)&sl[w * 16 + m][quad * 8];
        const bf16x8 af1 = *(const bf16x8*)&sl[w * 16 + m][32 + quad * 8];
        acc0 = __builtin_amdgcn_mfma_f32_16x16x32_bf16(af0, bv00, acc0, 0, 0, 0);
        acc1 = __builtin_amdgcn_mfma_f32_16x16x32_bf16(af0, bv01, acc1, 0, 0, 0);
        acc0 = __builtin_amdgcn_mfma_f32_16x16x32_bf16(af1, bv10, acc0, 0, 0, 0);
        acc1 = __builtin_amdgcn_mfma_f32_16x16x32_bf16(af1, bv11, acc1, 0, 0, 0);
        __builtin_amdgcn_s_setprio(0);
    }

    // epilogue: atomic accumulate partials onto out (pre-set to x; gamma in Vt)
    #pragma unroll
    for (int reg = 0; reg < 4; ++reg) {
        const int row = i0 + w * 16 + quad * 4 + reg;
        float* op = out + ((size_t)b * 4096 + row) * 32 + m;
        atomicAdd(op,      acc0[reg]);
        atomicAdd(op + 16, acc1[reg]);
    }
}

// ---------------------------------------------------------------------------
extern "C" void kernel_launch(void* const* d_in, const int* in_sizes, int n_in,
                              void* d_out, int out_size, void* d_ws, size_t ws_size,
                              hipStream_t stream)
{
    const float* x     = (const float*)d_in[0];
    const float* gamma = (const float*)d_in[1];
    const float* qw = (const float*)d_in[2];
    const float* qb = (const float*)d_in[3];
    const float* qs = (const float*)d_in[4];
    const float* qo = (const float*)d_in[5];
    const float* kw = (const float*)d_in[6];
    const float* kb = (const float*)d_in[7];
    const float* ks = (const float*)d_in[8];
    const float* ko = (const float*)d_in[9];
    const float* jw = (const float*)d_in[10];
    const float* jb = (const float*)d_in[11];
    const float* js = (const float*)d_in[12];
    const float* jo = (const float*)d_in[13];
    const float* vw = (const float*)d_in[14];
    const float* vb = (const float*)d_in[15];
    const float* vs = (const float*)d_in[16];
    const float* vo = (const float*)d_in[17];

    float* ws = (float*)d_ws;
    float* Qf = ws;                                   // 65536 floats
    float* Kf = ws + 65536;                           // 65536
    float* Jf = ws + 131072;                          // 65536
    float* Mp = ws + 196608;                          // 1024 (8 octant slices)
    unsigned short* Vt = (unsigned short*)(ws + 197632); // 262144 bf16 (16B-aligned)

    kA<<<1024, 256, 0, stream>>>(x, qw, qb, qs, qo, kw, kb, ks, ko,
                                 jw, jb, js, jo, vw, vb, vs, vo, gamma,
                                 Qf, Kf, Jf, Vt, (float*)d_out);
    kM<<<16, 256, 0, stream>>>(Kf, Jf, Mp);
    kD<<<1024, 256, 0, stream>>>(Qf, Mp, Kf, Vt, (float*)d_out);
}

// Round 7
// 132.257 us; speedup vs baseline: 1.0169x; 1.0100x over previous
//
#include <hip/hip_runtime.h>
#include <cstddef>

// Problem constants: (B,W,D,H,C) = (2,16,16,16,32), N = 4096 per batch.
//
// Reference-semantics note (R2 post-mortem): reshape(B,-1,N) is a row-major
// FLAT reshape: K[r][n] = Kflat[r*4096+n], Kflat[sp*8+ch] natural projection
// order. Qf/Kf/Jf stored FLAT, consumed as [r*4096+n] — that IS the reference.
// M[r][s] = sum_n Kflat[r*4096+n]*Jflat[s*4096+n] (cross-spatial pairing),
// computed exactly in kM. Sigmoid is ~saturated for typical rows but tail rows
// accumulate sum_j delta*V ~ O(1): z must be reference-exact per-row.
// R4 confirmed: exact M gives absmax 0.03125 (bf16-V random-walk floor).
//
// R5 post-mortem: cooperative-kernel fusion -> partial staleness (cross-XCD
// visibility, Guideline 16). Dispatch boundaries are the trustworthy fence.
// R6 post-mortem: kM at 16 blocks was a ~10 us serialization bubble (94% of
// the GPU idle, 256 KB/block at ~25 GB/s per-CU BW, un-overlappable between
// kA and kD). R7: kM widened to 128 blocks (64 KB/block, ~2-3 us).

typedef short bf16x8 __attribute__((ext_vector_type(8)));
typedef float f32x4 __attribute__((ext_vector_type(4)));

__device__ __forceinline__ unsigned short f2bf(float f) {
    union { float f; unsigned u; } v; v.f = f;
    unsigned r = v.u + 0x7fffu + ((v.u >> 16) & 1u);   // RNE
    return (unsigned short)(r >> 16);
}

// ---------------------------------------------------------------------------
// Kernel A: fused Q/K/J/V projections + out=x passthrough.
// Grid 1024 x 256 threads = 8 spatial points x 32 groups.
// Outputs:
//   Qf,Kf,Jf fp32 flat [b][sp*8+ch]  (reference reshape semantics)
//   Vt bf16 [b][c*4096+sp], gamma pre-folded
//   out = x (replaces the D2D memcpy dispatch)
// ---------------------------------------------------------------------------
__global__ __launch_bounds__(256) void kA(
    const float* __restrict__ x,
    const float* __restrict__ qw, const float* __restrict__ qb,
    const float* __restrict__ qs, const float* __restrict__ qo,
    const float* __restrict__ kw, const float* __restrict__ kb,
    const float* __restrict__ ks, const float* __restrict__ ko,
    const float* __restrict__ jw, const float* __restrict__ jb,
    const float* __restrict__ js, const float* __restrict__ jo,
    const float* __restrict__ vw, const float* __restrict__ vb,
    const float* __restrict__ vs, const float* __restrict__ vo,
    const float* __restrict__ gamma,
    float* __restrict__ Qf, float* __restrict__ Kf, float* __restrict__ Jf,
    unsigned short* __restrict__ Vt, float* __restrict__ out)
{
    __shared__ float vw_s[1024];        // [ci][co]
    __shared__ float cw_s[3 * 776];     // conv weights [conv][tap*256+ci*8+co]
    const int t = threadIdx.x;
    for (int i = t; i < 1024; i += 256) vw_s[i] = vw[i];
    for (int i = t; i < 768; i += 256) {
        cw_s[i]        = qw[i];
        cw_s[776 + i]  = kw[i];
        cw_s[1552 + i] = jw[i];
    }
    __syncthreads();

    const int spi = t >> 5;                     // 8 spatial points per block
    const int g   = t & 31;                     // 32 groups per point
    const int gsp = blockIdx.x * 8 + spi;       // b*4096+sp (b uniform per block)
    const int b   = gsp >> 12;
    const int sp  = gsp & 4095;
    const int w = sp >> 8, d = (sp >> 4) & 15, h = sp & 15;
    const float gm = gamma[0];
    const float4* xr = (const float4*)(x + (size_t)gsp * 32);

    // own x row in registers (shared by V-dot, center tap, and out passthrough)
    float4 xv[8];
    #pragma unroll
    for (int c8 = 0; c8 < 8; ++c8) xv[c8] = xr[c8];

    // out = x (each thread writes its one element; coalesced)
    {
        const float4 mine = xv[g >> 2];
        const int q = g & 3;
        const float xe = (q == 0) ? mine.x : (q == 1) ? mine.y : (q == 2) ? mine.z : mine.w;
        out[(size_t)gsp * 32 + g] = xe;
    }

    // ---- V (pointwise 32->32): one output channel (co=g) per thread ----
    {
        float a0 = 0.f, a1 = 0.f, a2 = 0.f, a3 = 0.f;
        #pragma unroll
        for (int c8 = 0; c8 < 8; ++c8) {
            const float4 v = xv[c8];
            a0 += v.x * vw_s[(c8 * 4 + 0) * 32 + g];
            a1 += v.y * vw_s[(c8 * 4 + 1) * 32 + g];
            a2 += v.z * vw_s[(c8 * 4 + 2) * 32 + g];
            a3 += v.w * vw_s[(c8 * 4 + 3) * 32 + g];
        }
        const float vv = fmaxf(((a0 + a1) + (a2 + a3) + vb[g]) * vs[g] + vo[g], 0.f) * gm;
        Vt[(size_t)b * 131072 + (size_t)g * 4096 + sp] = f2bf(vv);
    }

    // ---- Q/K/J (3-tap 1-D convs along d/w/h): one output per thread, g<24 ----
    if (g < 24) {
        const int conv = g >> 3;               // 0=Q(d), 1=K(w), 2=J(h)
        const int co   = g & 7;
        const int coord  = (conv == 0) ? d : (conv == 1) ? w : h;
        const int stride = (conv == 0) ? 16 : (conv == 1) ? 256 : 1;
        const float* cw = cw_s + conv * 776 + co;
        float b0 = 0.f, b1 = 0.f, b2 = 0.f, b3 = 0.f;
        #pragma unroll
        for (int tap = 0; tap < 3; ++tap) {
            const int cc = coord + tap - 1;
            if (cc < 0 || cc > 15) continue;           // SAME zero-pad
            const float4* xt = (const float4*)(x + (size_t)(gsp + (tap - 1) * stride) * 32);
            const float* wt = cw + tap * 256;
            #pragma unroll
            for (int c8 = 0; c8 < 8; ++c8) {
                const float4 v = (tap == 1) ? xv[c8] : xt[c8];  // center tap from regs
                b0 += v.x * wt[(c8 * 4 + 0) * 8];
                b1 += v.y * wt[(c8 * 4 + 1) * 8];
                b2 += v.z * wt[(c8 * 4 + 2) * 8];
                b3 += v.w * wt[(c8 * 4 + 3) * 8];
            }
        }
        const float* bbp = (conv == 0) ? qb : (conv == 1) ? kb : jb;
        const float* scp = (conv == 0) ? qs : (conv == 1) ? ks : js;
        const float* oop = (conv == 0) ? qo : (conv == 1) ? ko : jo;
        const float rv = fmaxf(((b0 + b1) + (b2 + b3) + bbp[co]) * scp[co] + oop[co], 0.f);
        float* dst = (conv == 0) ? Qf : (conv == 1) ? Kf : Jf;
        dst[(size_t)b * 32768 + (size_t)sp * 8 + co] = rv;   // FLAT (reference)
    }
}

// ---------------------------------------------------------------------------
// Kernel M: exact reference M = K@Jt on the flat matrices, 64 column-slices.
// Mp[(b*64 + r*8 + s)*64 + sl] = sum_{n in slice sl} Kflat[r*4096+n]*Jflat[s*4096+n].
// Grid 128 blocks (b*64+slice, 64 cols each) x 256 threads; 64 KB read/block
// (was 16 blocks x 256 KB: a ~10 us latency bubble on the kA->kD critical
// path with 94% of the GPU idle). Plain disjoint stores; no pre-zero.
// ---------------------------------------------------------------------------
__global__ __launch_bounds__(256) void kM(
    const float* __restrict__ Kf, const float* __restrict__ Jf,
    float* __restrict__ Mp)
{
    const int b = blockIdx.x >> 6, sl = blockIdx.x & 63;
    const int t = threadIdx.x;
    const int rs = t & 63, r = rs >> 3, s = rs & 7, sub = t >> 6;
    const float4* Kb = (const float4*)(Kf + (size_t)b * 32768 + (size_t)r * 4096 + sl * 64 + sub * 16);
    const float4* Jb = (const float4*)(Jf + (size_t)b * 32768 + (size_t)s * 4096 + sl * 64 + sub * 16);
    float acc = 0.f;
    #pragma unroll
    for (int i = 0; i < 4; ++i) {
        const float4 kv = Kb[i];
        const float4 jv = Jb[i];
        acc += kv.x * jv.x + kv.y * jv.y + kv.z * jv.z + kv.w * jv.w;
    }
    __shared__ float sm[256];
    sm[t] = acc;
    __syncthreads();
    if (t < 64)
        Mp[(size_t)(b * 64 + t) * 64 + sl] =
            sm[t] + sm[t + 64] + sm[t + 128] + sm[t + 192];
}

// ---------------------------------------------------------------------------
// Kernel D: out[b][i][c] += sum_{j in split} sigmoid(P_i.Kcol_j) * (gamma*V)[j][c]
// (out pre-initialized to x by kA; gamma folded into Vt by kA.)
// Block: 256 threads = 4 waves, TI=64 rows, j-split of 512 (8 chunks of 64).
// Grid: 2b x 64 rowtiles x 8 jsplits = 1024 blocks (LDS ~35 KB).
// Verified layouts (m89/m120): A[m=lane&15][k=quad*8+j]; B[k=quad*8+j][n=lane&15];
// C/D: col=lane&15, row=quad*4+reg.
// ---------------------------------------------------------------------------
__global__ __launch_bounds__(256) void kD(
    const float* __restrict__ Qf, const float* __restrict__ Mp,
    const float* __restrict__ Kf, const unsigned short* __restrict__ Vt,
    float* __restrict__ out)
{
    const int blk = blockIdx.x;
    const int jsp = blk & 7;
    const int rt  = (blk >> 3) & 63;
    const int b   = blk >> 9;
    const int i0  = rt * 64;
    const int j0  = jsp * 512;
    const int t   = threadIdx.x;
    // phase-1 mapping: 16 rowgroups (4 rows) x 16 jgroups (4 j)
    const int jg = t & 15, rg = t >> 4;
    // phase-2 mapping: wave w covers rows w*16..w*16+15
    const int w = t >> 6, lane = t & 63;
    const int m = lane & 15, quad = lane >> 4;

    __shared__ float m_s[64];
    __shared__ float kt_s[8][516];              // whole K chunk [r][j0-relative j]
    __shared__ unsigned short s_lds[2][64][72]; // sigmoid tile bf16, double-buffered

    const float* Kb = Kf + (size_t)b * 32768;
    const unsigned short* Vb = Vt + (size_t)b * 131072;

    if (t < 64) {
        const float4* mp = (const float4*)(Mp + (size_t)(b * 64 + t) * 64);
        float4 s4 = mp[0];
        #pragma unroll
        for (int o = 1; o < 16; ++o) {
            const float4 v = mp[o];
            s4.x += v.x; s4.y += v.y; s4.z += v.z; s4.w += v.w;
        }
        m_s[t] = (s4.x + s4.y) + (s4.z + s4.w);
    }
    #pragma unroll
    for (int v = 0; v < 4; ++v) {               // stage 8x512 fp32 K rows once
        const int idx = t + v * 256;            // 0..1023 float4s
        const int r = idx >> 7, j4 = (idx & 127) << 2;
        *(float4*)&kt_s[r][j4] = *(const float4*)(Kb + (size_t)r * 4096 + j0 + j4);
    }
    __syncthreads();

    // P2[4 rows][8] = -log2(e) * (Qt-rows . M); Qt[i][r] = Qflat[r*4096+i]
    float P2[4][8];
    {
        float a[4][8];
        #pragma unroll
        for (int r = 0; r < 8; ++r) {
            const float4 qv = *(const float4*)(Qf + (size_t)b * 32768 + (size_t)r * 4096 + i0 + rg * 4);
            a[0][r] = qv.x; a[1][r] = qv.y; a[2][r] = qv.z; a[3][r] = qv.w;
        }
        #pragma unroll
        for (int s = 0; s < 8; ++s) {
            #pragma unroll
            for (int ri = 0; ri < 4; ++ri) {
                float acc = 0.f;
                #pragma unroll
                for (int r = 0; r < 8; ++r) acc += a[ri][r] * m_s[r * 8 + s];
                P2[ri][s] = acc * -1.44269504f;
            }
        }
    }

    f32x4 acc0 = {0.f, 0.f, 0.f, 0.f};
    f32x4 acc1 = {0.f, 0.f, 0.f, 0.f};

    #pragma unroll 1
    for (int jc = 0; jc < 8; ++jc) {
        const int jb = j0 + jc * 64;
        // prefetch B frags; the barrier's vmcnt(0) drain is exactly their use site
        const bf16x8 bv00 = *(const bf16x8*)(Vb + (size_t)m * 4096 + jb + quad * 8);
        const bf16x8 bv10 = *(const bf16x8*)(Vb + (size_t)m * 4096 + jb + 32 + quad * 8);
        const bf16x8 bv01 = *(const bf16x8*)(Vb + (size_t)(16 + m) * 4096 + jb + quad * 8);
        const bf16x8 bv11 = *(const bf16x8*)(Vb + (size_t)(16 + m) * 4096 + jb + 32 + quad * 8);

        unsigned short (*sl)[72] = s_lds[jc & 1];

        // phase 1: 16 sigmoids per thread (4 rows x 4 j), bf16 tile to sl
        unsigned hpk[4][2];
        {
            f32x4 pa[4];
            #pragma unroll
            for (int ri = 0; ri < 4; ++ri) pa[ri] = (f32x4){0.f, 0.f, 0.f, 0.f};
            #pragma unroll
            for (int r = 0; r < 8; ++r) {
                const f32x4 kv = *(const f32x4*)&kt_s[r][(jc << 6) + (jg << 2)];
                #pragma unroll
                for (int ri = 0; ri < 4; ++ri) {
                    const float p = P2[ri][r];
                    pa[ri][0] += p * kv[0];
                    pa[ri][1] += p * kv[1];
                    pa[ri][2] += p * kv[2];
                    pa[ri][3] += p * kv[3];
                }
            }
            #pragma unroll
            for (int ri = 0; ri < 4; ++ri) {
                float e0, e1, e2, e3;
                asm("v_exp_f32 %0, %1" : "=v"(e0) : "v"(pa[ri][0]));
                asm("v_exp_f32 %0, %1" : "=v"(e1) : "v"(pa[ri][1]));
                asm("v_exp_f32 %0, %1" : "=v"(e2) : "v"(pa[ri][2]));
                asm("v_exp_f32 %0, %1" : "=v"(e3) : "v"(pa[ri][3]));
                const float s0 = __builtin_amdgcn_rcpf(1.0f + e0);
                const float s1 = __builtin_amdgcn_rcpf(1.0f + e1);
                const float s2 = __builtin_amdgcn_rcpf(1.0f + e2);
                const float s3 = __builtin_amdgcn_rcpf(1.0f + e3);
                unsigned pk0, pk1;
                asm("v_cvt_pk_bf16_f32 %0, %1, %2" : "=v"(pk0) : "v"(s0), "v"(s1));
                asm("v_cvt_pk_bf16_f32 %0, %1, %2" : "=v"(pk1) : "v"(s2), "v"(s3));
                hpk[ri][0] = pk0;
                hpk[ri][1] = pk1;
            }
        }
        #pragma unroll
        for (int ri = 0; ri < 4; ++ri)
            *(uint2*)&sl[rg * 4 + ri][jg * 4] = make_uint2(hpk[ri][0], hpk[ri][1]);

        __syncthreads();

        // phase 2: 4 MFMAs per wave (2 k-tiles x 2 n-tiles), B from regs
        __builtin_amdgcn_s_setprio(1);
        const bf16x8 af0 = *(const bf16x8*)&sl[w * 16 + m][quad * 8];
        const bf16x8 af1 = *(const bf16x8*)&sl[w * 16 + m][32 + quad * 8];
        acc0 = __builtin_amdgcn_mfma_f32_16x16x32_bf16(af0, bv00, acc0, 0, 0, 0);
        acc1 = __builtin_amdgcn_mfma_f32_16x16x32_bf16(af0, bv01, acc1, 0, 0, 0);
        acc0 = __builtin_amdgcn_mfma_f32_16x16x32_bf16(af1, bv10, acc0, 0, 0, 0);
        acc1 = __builtin_amdgcn_mfma_f32_16x16x32_bf16(af1, bv11, acc1, 0, 0, 0);
        __builtin_amdgcn_s_setprio(0);
    }

    // epilogue: atomic accumulate partials onto out (pre-set to x; gamma in Vt)
    #pragma unroll
    for (int reg = 0; reg < 4; ++reg) {
        const int row = i0 + w * 16 + quad * 4 + reg;
        float* op = out + ((size_t)b * 4096 + row) * 32 + m;
        atomicAdd(op,      acc0[reg]);
        atomicAdd(op + 16, acc1[reg]);
    }
}

// ---------------------------------------------------------------------------
extern "C" void kernel_launch(void* const* d_in, const int* in_sizes, int n_in,
                              void* d_out, int out_size, void* d_ws, size_t ws_size,
                              hipStream_t stream)
{
    const float* x     = (const float*)d_in[0];
    const float* gamma = (const float*)d_in[1];
    const float* qw = (const float*)d_in[2];
    const float* qb = (const float*)d_in[3];
    const float* qs = (const float*)d_in[4];
    const float* qo = (const float*)d_in[5];
    const float* kw = (const float*)d_in[6];
    const float* kb = (const float*)d_in[7];
    const float* ks = (const float*)d_in[8];
    const float* ko = (const float*)d_in[9];
    const float* jw = (const float*)d_in[10];
    const float* jb = (const float*)d_in[11];
    const float* js = (const float*)d_in[12];
    const float* jo = (const float*)d_in[13];
    const float* vw = (const float*)d_in[14];
    const float* vb = (const float*)d_in[15];
    const float* vs = (const float*)d_in[16];
    const float* vo = (const float*)d_in[17];

    float* ws = (float*)d_ws;
    float* Qf = ws;                                   // 65536 floats
    float* Kf = ws + 65536;                           // 65536
    float* Jf = ws + 131072;                          // 65536
    float* Mp = ws + 196608;                          // 8192 (128 entries x 64 slices)
    unsigned short* Vt = (unsigned short*)(ws + 204800); // 262144 bf16 (16B-aligned)

    kA<<<1024, 256, 0, stream>>>(x, qw, qb, qs, qo, kw, kb, ks, ko,
                                 jw, jb, js, jo, vw, vb, vs, vo, gamma,
                                 Qf, Kf, Jf, Vt, (float*)d_out);
    kM<<<128, 256, 0, stream>>>(Kf, Jf, Mp);
    kD<<<1024, 256, 0, stream>>>(Qf, Mp, Kf, Vt, (float*)d_out);
}